// Round 11
// baseline (55.724 us; speedup 1.0000x reference)
//
#include <hip/hip_runtime.h>

// Causal MHA forward: B=2 H=16 T=2048 DH=64, fp32 in/out, bf16 MFMA math.
// Round-6 schedule (grid 1024 LPT, 4 waves, KBLK=64, dbuf, 1 barrier/iter,
// T14 reg-prefetch, T5 setprio) with the softmax cross-lane ops removed
// from the common path:
//  - per-lane partial l (reduced across g-replicas ONCE in the epilogue)
//  - defer-max check uses LOCAL 16-value max only (__all makes it exactly
//    equivalent to the old global check); cross-lane max + O-rescale run
//    only when triggered.

constexpr int Bc = 2, Hc = 16, Tc = 2048, Dc = 64;
constexpr float QSCALE = 0.125f * 1.44269504088896340736f; // DH^-0.5 * log2 e

typedef __attribute__((__ext_vector_type__(8))) __bf16 bf16x8;
typedef __attribute__((__ext_vector_type__(4))) __bf16 bf16x4;
typedef __attribute__((__ext_vector_type__(4))) float f32x4;

__global__ __launch_bounds__(256, 4) void attn_fwd_kernel(
    const float* __restrict__ Q,
    const float* __restrict__ K,
    const float* __restrict__ V,
    float* __restrict__ O)
{
  const int tid  = threadIdx.x;
  const int wave = tid >> 6;
  const int lane = tid & 63;
  const int l16  = lane & 15;
  const int g    = lane >> 4;

  const int bid   = blockIdx.x;
  const int head  = bid & 31;           // co-resident blocks share head
  const int qtile = 31 - (bid >> 5);    // LPT: longest first
  const int b = head >> 4, h = head & 15;
  const int q0 = qtile * 64 + wave * 16;

  const size_t hoff = (size_t)head * Tc * Dc;
  const float* Qb = Q + hoff;
  const float* Kb = K + hoff;
  const float* Vb = V + hoff;

  // K tile [64 k][64 d] bf16, 128 B rows, byte ^ ((k&7)<<4) swizzle.
  __shared__ __bf16 Kl[2][64 * 64];
  // V^T k-quads: addr(kc,d) = kc*512 + ((d*8) ^ (kc<<3) ^ (((d>>4)&3)<<3))
  // + 2*(k&3). Conflict-free b64 writes and floor reads.
  __shared__ __bf16 Vt[2][64 * 64];

  const int krow = tid >> 2;          // K staging: row; seg = 16-float chunk
  const int seg  = tid & 3;
  const int kswz = (krow & 7) << 4;
  const int vkb  = tid >> 4;          // V staging: k-quad block
  const int vdb  = tid & 15;          // V staging: d-quad
  const int vwx  = (vdb >> 2) << 3;

  // Q as B-operand frag of S^T = K·Q^T: lane l16 = q, regs d = c*32+g*8+j.
  bf16x8 qf[2];
  {
    const float4* qp = (const float4*)(Qb + (size_t)(q0 + l16) * Dc + g * 8);
    #pragma unroll
    for (int c = 0; c < 2; ++c) {
      float4 x0 = qp[c * 8], x1 = qp[c * 8 + 1];
      const float* f0 = (const float*)&x0;
      const float* f1 = (const float*)&x1;
      #pragma unroll
      for (int j = 0; j < 4; ++j) {
        qf[c][j]     = (__bf16)(f0[j] * QSCALE);
        qf[c][4 + j] = (__bf16)(f1[j] * QSCALE);
      }
    }
  }

  f32x4 o_acc[4] = {};
  float m_run = -1e30f;
  float l_part = 0.f;                 // per-lane partial sum (this replica)
  const int n_iter = qtile + 1;
  float4 kreg[4], vreg[4];

  // ---- Prologue: tile 0 -> regs -> buf 0 ----
  {
    const float4* kp4 = (const float4*)(Kb + (size_t)krow * Dc + seg * 16);
    #pragma unroll
    for (int c = 0; c < 4; ++c) kreg[c] = kp4[c];
    const float* vb0 = Vb + (size_t)(vkb * 4) * Dc + vdb * 4;
    #pragma unroll
    for (int r = 0; r < 4; ++r) vreg[r] = *(const float4*)(vb0 + r * Dc);

    #pragma unroll
    for (int hh = 0; hh < 2; ++hh) {
      const float* x0 = (const float*)&kreg[2 * hh];
      const float* x1 = (const float*)&kreg[2 * hh + 1];
      bf16x8 t;
      #pragma unroll
      for (int j = 0; j < 4; ++j) { t[j] = (__bf16)x0[j]; t[4 + j] = (__bf16)x1[j]; }
      *(bf16x8*)((char*)Kl[0] + krow * 128 + ((seg * 32 + hh * 16) ^ kswz)) = t;
    }
    #pragma unroll
    for (int i = 0; i < 4; ++i) {
      bf16x4 t;
      #pragma unroll
      for (int r = 0; r < 4; ++r) t[r] = (__bf16)((const float*)&vreg[r])[i];
      const int d = vdb * 4 + i;
      *(bf16x4*)((char*)Vt[0] + vkb * 512 + ((d * 8) ^ (vkb << 3) ^ vwx)) = t;
    }
  }

  for (int it = 0; it < n_iter; ++it) {
    __syncthreads();   // buf[cur] staged; other buffer free
    const int cur = it & 1;

    // ---- T14: next tile's global loads land during compute ----
    const bool more = (it + 1 < n_iter);
    if (more) {
      const int kv1 = (it + 1) * 64;
      const float4* kp4 = (const float4*)(Kb + (size_t)(kv1 + krow) * Dc + seg * 16);
      #pragma unroll
      for (int c = 0; c < 4; ++c) kreg[c] = kp4[c];
      const float* vb0 = Vb + (size_t)(kv1 + vkb * 4) * Dc + vdb * 4;
      #pragma unroll
      for (int r = 0; r < 4; ++r) vreg[r] = *(const float4*)(vb0 + r * Dc);
    }

    const bool partial = (it == qtile);
    const int  ns = partial ? (wave + 1) : 4;

    // ---- S^T = K·Q^T: sacc[s] k = s*16+g*4+r, q = l16 ----
    f32x4 sacc[4];
    __builtin_amdgcn_s_setprio(1);
    #pragma unroll
    for (int s = 0; s < 4; ++s) {
      if (s < ns) {  // wave-uniform
        f32x4 z = {0.f, 0.f, 0.f, 0.f};
        const int row = s * 16 + l16;
        const char* kb = (const char*)Kl[cur] + row * 128;
        const int swz = (row & 7) << 4;
        bf16x8 k0 = *(const bf16x8*)(kb + ((g * 16) ^ swz));
        bf16x8 k1 = *(const bf16x8*)(kb + ((64 + g * 16) ^ swz));
        z = __builtin_amdgcn_mfma_f32_16x16x32_bf16(k0, qf[0], z, 0, 0, 0);
        z = __builtin_amdgcn_mfma_f32_16x16x32_bf16(k1, qf[1], z, 0, 0, 0);
        sacc[s] = z;
      } else {
        sacc[s] = f32x4{-INFINITY, -INFINITY, -INFINITY, -INFINITY};
      }
    }
    __builtin_amdgcn_s_setprio(0);
    if (partial) {  // diagonal mask
      #pragma unroll
      for (int s = 0; s < 4; ++s)
        #pragma unroll
        for (int r = 0; r < 4; ++r)
          if (s * 16 + g * 4 + r > wave * 16 + l16) sacc[s][r] = -INFINITY;
    }

    // ---- Local max (tree, no cross-lane on the common path) ----
    float v16[16];
    #pragma unroll
    for (int s = 0; s < 4; ++s)
      #pragma unroll
      for (int r = 0; r < 4; ++r) v16[s * 4 + r] = sacc[s][r];
    #pragma unroll
    for (int w = 8; w >= 1; w >>= 1)
      #pragma unroll
      for (int i = 0; i < 8; ++i)
        if (i < w) v16[i] = fmaxf(v16[i], v16[i + w]);
    const float mxl = v16[0];

    // Defer-max: __all over 64 lanes == old global-max check exactly.
    if (!__all(mxl <= m_run + 8.0f)) {
      float mx = fmaxf(mxl, __shfl_xor(mxl, 16, 64));
      mx = fmaxf(mx, __shfl_xor(mx, 32, 64));
      const float mn = fmaxf(m_run, mx);
      const float f  = __builtin_amdgcn_exp2f(m_run - mn);
      m_run = mn;
      l_part *= f;
      #pragma unroll
      for (int r = 0; r < 4; ++r) {
        const float fo = __shfl(f, g * 4 + r, 64);
        #pragma unroll
        for (int dt = 0; dt < 4; ++dt) o_acc[dt][r] *= fo;
      }
    }

    // ---- exps + per-lane partial sum (no cross-lane) ----
    float pv16[16];
    bf16x8 pa[2];
    #pragma unroll
    for (int c = 0; c < 2; ++c)
      #pragma unroll
      for (int j = 0; j < 8; ++j) {
        const float pv = __builtin_amdgcn_exp2f(sacc[2 * c + (j >> 2)][j & 3] - m_run);
        pv16[c * 8 + j] = pv;
        pa[c][j] = (__bf16)pv;
      }
    #pragma unroll
    for (int w = 8; w >= 1; w >>= 1)
      #pragma unroll
      for (int i = 0; i < 8; ++i)
        if (i < w) pv16[i] += pv16[i + w];
    l_part += pv16[0];

    // ---- PV: O += P(16x64)·V(64x64), both operands in pi k-order ----
    __builtin_amdgcn_s_setprio(1);
    #pragma unroll
    for (int dt = 0; dt < 4; ++dt) {
      const int d = dt * 16 + l16;
      const int dx = (dt & 3) << 3;
      #pragma unroll
      for (int c = 0; c < 2; ++c) {
        const int kc0 = 8 * c + g;
        const int kc1 = 8 * c + 4 + g;
        union { bf16x8 v8; bf16x4 v4[2]; } uu;
        uu.v4[0] = *(const bf16x4*)((char*)Vt[cur] + kc0 * 512 + ((d * 8) ^ (kc0 << 3) ^ dx));
        uu.v4[1] = *(const bf16x4*)((char*)Vt[cur] + kc1 * 512 + ((d * 8) ^ (kc1 << 3) ^ dx));
        o_acc[dt] = __builtin_amdgcn_mfma_f32_16x16x32_bf16(pa[c], uu.v8, o_acc[dt], 0, 0, 0);
      }
    }
    __builtin_amdgcn_s_setprio(0);

    // ---- Write prefetched tile into the other buffer ----
    if (more) {
      const int nxt = cur ^ 1;
      #pragma unroll
      for (int hh = 0; hh < 2; ++hh) {
        const float* x0 = (const float*)&kreg[2 * hh];
        const float* x1 = (const float*)&kreg[2 * hh + 1];
        bf16x8 t;
        #pragma unroll
        for (int j = 0; j < 4; ++j) { t[j] = (__bf16)x0[j]; t[4 + j] = (__bf16)x1[j]; }
        *(bf16x8*)((char*)Kl[nxt] + krow * 128 + ((seg * 32 + hh * 16) ^ kswz)) = t;
      }
      #pragma unroll
      for (int i = 0; i < 4; ++i) {
        bf16x4 t;
        #pragma unroll
        for (int r = 0; r < 4; ++r) t[r] = (__bf16)((const float*)&vreg[r])[i];
        const int d = vdb * 4 + i;
        *(bf16x4*)((char*)Vt[nxt] + vkb * 512 + ((d * 8) ^ (vkb << 3) ^ vwx)) = t;
      }
    }
  }

  // ---- Epilogue: reduce l across the 4 g-replicas ONCE, then store ----
  float l_run = l_part;
  l_run += __shfl_xor(l_run, 16, 64);
  l_run += __shfl_xor(l_run, 32, 64);

  #pragma unroll
  for (int r = 0; r < 4; ++r) {
    const float il = __shfl(l_run, g * 4 + r, 64);
    const float inv = 1.f / il;
    float* orow = O + ((size_t)b * Tc + (q0 + g * 4 + r)) * (Hc * Dc) + h * Dc;
    #pragma unroll
    for (int dt = 0; dt < 4; ++dt)
      orow[dt * 16 + l16] = o_acc[dt][r] * inv;
  }
}

extern "C" void kernel_launch(void* const* d_in, const int* in_sizes, int n_in,
                              void* d_out, int out_size, void* d_ws, size_t ws_size,
                              hipStream_t stream) {
  const float* q = (const float*)d_in[0];
  const float* k = (const float*)d_in[1];
  const float* v = (const float*)d_in[2];
  float* out = (float*)d_out;

  dim3 grid(1024);  // 32 qtiles (longest first) x 32 heads
  dim3 block(256);  // 4 waves
  hipLaunchKernelGGL(attn_fwd_kernel, grid, block, 0, stream, q, k, v, out);
}